// Round 5
// baseline (1556.234 us; speedup 1.0000x reference)
//
#include <hip/hip_runtime.h>

#define TOK   8192
#define DIMD  768
#define NH    12
#define HD    64
#define NE    8
#define RK    16
#define O3    2304
#define KSIDE 192          // 136 used + zero pad so K_qkv = 768+192 = 960 = 15*64
#define KQKV  960
#define SCALING_F 2.0f
#define SM_SCALE 0.125f

typedef short  short8  __attribute__((ext_vector_type(8)));
typedef ushort ushort8 __attribute__((ext_vector_type(8)));
typedef float  f32x4   __attribute__((ext_vector_type(4)));

__device__ __forceinline__ ushort f2bf_rn(float f) {
    union { float f; uint u; } v; v.f = f;
    uint r = (v.u + 0x7FFFu + ((v.u >> 16) & 1u)) >> 16;
    return (ushort)r;
}
__device__ __forceinline__ void split_bf(float f, ushort& hi, ushort& lo) {
    hi = f2bf_rn(f);
    union { uint u; float f; } h; h.u = (uint)hi << 16;
    lo = f2bf_rn(f - h.f);
}

// ---------------- router: logits -> softmax -> top2 ----------------
__global__ __launch_bounds__(64) void router_kernel(
    const float* __restrict__ x, const float* __restrict__ Wg,
    const float* __restrict__ bg, float* __restrict__ topw, int* __restrict__ topidx)
{
    int t = blockIdx.x;
    int lane = threadIdx.x;
    const float* xr = x + (size_t)t * DIMD;
    float part[NE];
#pragma unroll
    for (int e = 0; e < NE; ++e) part[e] = 0.f;
#pragma unroll
    for (int i = 0; i < DIMD / 64; ++i) {
        int d = i * 64 + lane;
        float xv = xr[d];
#pragma unroll
        for (int e = 0; e < NE; ++e) part[e] += xv * Wg[e * DIMD + d];
    }
#pragma unroll
    for (int e = 0; e < NE; ++e) {
        float v = part[e];
#pragma unroll
        for (int off = 32; off > 0; off >>= 1) v += __shfl_xor(v, off);
        part[e] = v;
    }
    if (lane == 0) {
        float lg[NE], p[NE];
        float mx = -1e30f;
#pragma unroll
        for (int e = 0; e < NE; ++e) { lg[e] = part[e] + bg[e]; mx = fmaxf(mx, lg[e]); }
        float sum = 0.f;
#pragma unroll
        for (int e = 0; e < NE; ++e) { p[e] = __expf(lg[e] - mx); sum += p[e]; }
        float inv = 1.f / sum;
#pragma unroll
        for (int e = 0; e < NE; ++e) p[e] *= inv;
        int i0 = 0;
#pragma unroll
        for (int e = 1; e < NE; ++e) if (p[e] > p[i0]) i0 = e;
        int i1 = (i0 == 0) ? 1 : 0;
#pragma unroll
        for (int e = 0; e < NE; ++e) if (e != i0 && p[e] > p[i1]) i1 = e;
        topw[t * 2 + 0] = p[i0];
        topw[t * 2 + 1] = p[i1];
        topidx[t * 2 + 0] = i0;
        topidx[t * 2 + 1] = i1;
    }
}

// ---------------- LoRA h for the 2 selected experts, combine-weighted ----------------
__global__ __launch_bounds__(256) void lora_h_kernel(
    const float* __restrict__ x, const float* __restrict__ A, const float* __restrict__ ba,
    const float* __restrict__ topw, const int* __restrict__ topidx,
    float* __restrict__ hw2)
{
    __shared__ float xs[DIMD];
    int t = blockIdx.x;
    int tid = threadIdx.x;
    const float* xr = x + (size_t)t * DIMD;
    for (int i = tid; i < DIMD; i += 256) xs[i] = xr[i];
    __syncthreads();
    int outi = tid >> 3;     // 0..31  (k*16 + r)
    int sub  = tid & 7;
    int k = outi >> 4;
    int r = outi & 15;
    int e = topidx[t * 2 + k];
    float w = topw[t * 2 + k];
    const float* Ar = A + ((size_t)e * RK + r) * DIMD;
    float s = 0.f;
    for (int d = sub; d < DIMD; d += 8) s += xs[d] * Ar[d];
    s += __shfl_xor(s, 1);
    s += __shfl_xor(s, 2);
    s += __shfl_xor(s, 4);
    if (sub == 0) hw2[t * 32 + outi] = w * (s + ba[e * RK + r]);
}

// ---------------- dense side-matrix for X: [hw dense(128) | combine(8) | pad] ----------------
__global__ __launch_bounds__(64) void build_xside(
    const float* __restrict__ hw2, const float* __restrict__ topw,
    const int* __restrict__ topidx, float* __restrict__ xside)
{
    int t = blockIdx.x;
    int tid = threadIdx.x;
    float* xr = xside + (size_t)t * KSIDE;
    for (int i = tid; i < KSIDE; i += 64) xr[i] = 0.f;
    __syncthreads();
    if (tid < 32) {
        int k = tid >> 4, r = tid & 15;
        int e = topidx[t * 2 + k];
        xr[e * 16 + r] = hw2[t * 32 + tid];
    } else if (tid < 34) {
        int k = tid - 32;
        xr[128 + topidx[t * 2 + k]] = topw[t * 2 + k];
    }
}

// ---------------- side-matrix for W: [SCALING*Bm(128) | SCALING*bb(8) | pad] ----------------
__global__ __launch_bounds__(192) void build_wside(
    const float* __restrict__ Bm, const float* __restrict__ bb, float* __restrict__ wside)
{
    int o = blockIdx.x;
    int c = threadIdx.x;
    float v;
    if (c < 128) {
        int e = c >> 4, r = c & 15;
        v = SCALING_F * Bm[((size_t)e * O3 + o) * RK + r];
    } else if (c < 136) {
        v = SCALING_F * bb[(c - 128) * O3 + o];
    } else {
        v = 0.f;
    }
    wside[(size_t)o * KSIDE + c] = v;
}

// ---------------- convert combined X=[x|xside] to bf16 hi/lo [TOK][KQKV] ----------------
__global__ __launch_bounds__(256) void convert_x(
    const float* __restrict__ x, const float* __restrict__ xside,
    ushort* __restrict__ Xh, ushort* __restrict__ Xl)
{
    int idx = blockIdx.x * 256 + threadIdx.x;     // one thread per 8 cols
    int row = idx / (KQKV / 8);
    int cp  = idx % (KQKV / 8);
    int c = cp * 8;
    const float* src = (c < DIMD) ? (x + (size_t)row * DIMD + c)
                                  : (xside + (size_t)row * KSIDE + (c - DIMD));
    float4 v0 = *(const float4*)src;
    float4 v1 = *(const float4*)(src + 4);
    float vv[8] = {v0.x, v0.y, v0.z, v0.w, v1.x, v1.y, v1.z, v1.w};
    ushort8 h, l;
#pragma unroll
    for (int i = 0; i < 8; ++i) { ushort hh, ll; split_bf(vv[i], hh, ll); h[i] = hh; l[i] = ll; }
    *(ushort8*)(Xh + (size_t)row * KQKV + c) = h;
    *(ushort8*)(Xl + (size_t)row * KQKV + c) = l;
}

// ---------------- convert combined Wqkv|wside to bf16 hi/lo [O3][KQKV] ----------------
__global__ __launch_bounds__(256) void convert_wqkv(
    const float* __restrict__ Wqkv, const float* __restrict__ wside,
    ushort* __restrict__ Wh, ushort* __restrict__ Wl)
{
    int idx = blockIdx.x * 256 + threadIdx.x;
    int row = idx / (KQKV / 8);
    int cp  = idx % (KQKV / 8);
    int c = cp * 8;
    const float* src = (c < DIMD) ? (Wqkv + (size_t)row * DIMD + c)
                                  : (wside + (size_t)row * KSIDE + (c - DIMD));
    float4 v0 = *(const float4*)src;
    float4 v1 = *(const float4*)(src + 4);
    float vv[8] = {v0.x, v0.y, v0.z, v0.w, v1.x, v1.y, v1.z, v1.w};
    ushort8 h, l;
#pragma unroll
    for (int i = 0; i < 8; ++i) { ushort hh, ll; split_bf(vv[i], hh, ll); h[i] = hh; l[i] = ll; }
    *(ushort8*)(Wh + (size_t)row * KQKV + c) = h;
    *(ushort8*)(Wl + (size_t)row * KQKV + c) = l;
}

// ---------------- convert Wproj to bf16 hi/lo [DIMD][DIMD] ----------------
__global__ __launch_bounds__(256) void convert_wproj(
    const float* __restrict__ Wp, ushort* __restrict__ Wh, ushort* __restrict__ Wl)
{
    int idx = blockIdx.x * 256 + threadIdx.x;
    int c = idx * 8;
    float4 v0 = *(const float4*)(Wp + c);
    float4 v1 = *(const float4*)(Wp + c + 4);
    float vv[8] = {v0.x, v0.y, v0.z, v0.w, v1.x, v1.y, v1.z, v1.w};
    ushort8 h, l;
#pragma unroll
    for (int i = 0; i < 8; ++i) { ushort hh, ll; split_bf(vv[i], hh, ll); h[i] = hh; l[i] = ll; }
    *(ushort8*)(Wh + c) = h;
    *(ushort8*)(Wl + c) = l;
}

// ---------------- bf16-split MFMA GEMM: C[M,N] = Asplit @ Bsplit^T + bias ----------------
// 3-product compensated: AhBh + AlBh + AhBl (AlBl ~2^-34, dropped).
// 128x128 tile, BK=64, 4 waves (2x2), 4x4 frags of mfma_f32_16x16x32_bf16.
// LDS XOR chunk swizzle: global chunk chk stored at slot chk^(row&7) -> conflict-free
// staging writes AND fragment ds_read_b128.
__global__ __launch_bounds__(256) void gemm_bf16(
    const ushort* __restrict__ Ahg, const ushort* __restrict__ Alg,
    const ushort* __restrict__ Bhg, const ushort* __restrict__ Blg,
    const float* __restrict__ bias, float* __restrict__ C,
    int N, int K)
{
    __shared__ __align__(16) ushort Ah[128 * 64];
    __shared__ __align__(16) ushort Al[128 * 64];
    __shared__ __align__(16) ushort Bh[128 * 64];
    __shared__ __align__(16) ushort Bl[128 * 64];
    const int tid = threadIdx.x;
    const int w = tid >> 6, l = tid & 63;
    const int lr = l & 15, lk = l >> 4;
    const int wm = w >> 1, wn = w & 1;
    const int row0 = blockIdx.y * 128, col0 = blockIdx.x * 128;

    f32x4 acc[4][4];
#pragma unroll
    for (int m = 0; m < 4; ++m)
#pragma unroll
        for (int n = 0; n < 4; ++n) acc[m][n] = (f32x4)(0.f);

    for (int kk = 0; kk < K; kk += 64) {
        __syncthreads();
#pragma unroll
        for (int i = 0; i < 4; ++i) {
            int q = i * 256 + tid;
            int row = q >> 3, s = q & 7;
            int chk = s ^ (row & 7);
            *(float4*)&Ah[row * 64 + s * 8] =
                *(const float4*)(Ahg + (size_t)(row0 + row) * K + kk + chk * 8);
            *(float4*)&Al[row * 64 + s * 8] =
                *(const float4*)(Alg + (size_t)(row0 + row) * K + kk + chk * 8);
            *(float4*)&Bh[row * 64 + s * 8] =
                *(const float4*)(Bhg + (size_t)(col0 + row) * K + kk + chk * 8);
            *(float4*)&Bl[row * 64 + s * 8] =
                *(const float4*)(Blg + (size_t)(col0 + row) * K + kk + chk * 8);
        }
        __syncthreads();
#pragma unroll
        for (int kh = 0; kh < 2; ++kh) {
            const int slot = (kh * 4 + lk) ^ (lr & 7);
            short8 af[4], alf[4], bf[4], blf[4];
#pragma unroll
            for (int m = 0; m < 4; ++m) {
                int r = wm * 64 + m * 16 + lr;
                af[m]  = *(const short8*)&Ah[r * 64 + slot * 8];
                alf[m] = *(const short8*)&Al[r * 64 + slot * 8];
            }
#pragma unroll
            for (int n = 0; n < 4; ++n) {
                int r = wn * 64 + n * 16 + lr;
                bf[n]  = *(const short8*)&Bh[r * 64 + slot * 8];
                blf[n] = *(const short8*)&Bl[r * 64 + slot * 8];
            }
#pragma unroll
            for (int m = 0; m < 4; ++m)
#pragma unroll
                for (int n = 0; n < 4; ++n)
                    acc[m][n] = __builtin_amdgcn_mfma_f32_16x16x32_bf16(af[m], bf[n], acc[m][n], 0, 0, 0);
#pragma unroll
            for (int m = 0; m < 4; ++m)
#pragma unroll
                for (int n = 0; n < 4; ++n)
                    acc[m][n] = __builtin_amdgcn_mfma_f32_16x16x32_bf16(alf[m], bf[n], acc[m][n], 0, 0, 0);
#pragma unroll
            for (int m = 0; m < 4; ++m)
#pragma unroll
                for (int n = 0; n < 4; ++n)
                    acc[m][n] = __builtin_amdgcn_mfma_f32_16x16x32_bf16(af[m], blf[n], acc[m][n], 0, 0, 0);
        }
    }
    // C/D layout: col = lane&15, row = (lane>>4)*4 + reg   [m89 verified]
#pragma unroll
    for (int n = 0; n < 4; ++n) {
        int cc = col0 + wn * 64 + n * 16 + lr;
        float bv = bias[cc];
#pragma unroll
        for (int m = 0; m < 4; ++m) {
#pragma unroll
            for (int j = 0; j < 4; ++j) {
                int rr = row0 + wm * 64 + m * 16 + lk * 4 + j;
                C[(size_t)rr * N + cc] = acc[m][n][j] + bv;
            }
        }
    }
}

// ---------------- flash attention: 8 q-rows x 8 dims per thread ----------------
// Writes output directly as split bf16 (hi/lo) for the proj MFMA GEMM.
__global__ __launch_bounds__(128) void attn_kernel(
    const float* __restrict__ qkv,
    ushort* __restrict__ Oh, ushort* __restrict__ Ol)
{
    __shared__ float Ks[32][72];   // row stride 288B: 16B aligned; 2-way bank alias (free)
    __shared__ float Vs[32][72];
    const int tid = threadIdx.x;
    const int gid = blockIdx.x;
    const int qb = gid & 7;             // 8 q-blocks of 128 rows
    const int h  = (gid >> 3) % NH;
    const int b  = gid / (8 * NH);
    const int t0 = b * 1024;
    const int grp = tid >> 3;           // 16 groups per block, 8 rows each
    const int qf  = tid & 7;            // 8-dim slice owner
    const int r0 = qb * 128 + grp * 8;  // first of this thread's 8 q-rows

    float q[8][8], acc[8][8], l[8];
#pragma unroll
    for (int j = 0; j < 8; ++j) {
        const float* qr = qkv + (size_t)(t0 + r0 + j) * O3 + h * HD + qf * 8;
        float4 a4 = *(const float4*)(qr);
        float4 b4 = *(const float4*)(qr + 4);
        q[j][0] = a4.x * SM_SCALE; q[j][1] = a4.y * SM_SCALE;
        q[j][2] = a4.z * SM_SCALE; q[j][3] = a4.w * SM_SCALE;
        q[j][4] = b4.x * SM_SCALE; q[j][5] = b4.y * SM_SCALE;
        q[j][6] = b4.z * SM_SCALE; q[j][7] = b4.w * SM_SCALE;
        l[j] = 0.f;
#pragma unroll
        for (int i = 0; i < 8; ++i) acc[j][i] = 0.f;
    }

    for (int kt = 0; kt < 32; ++kt) {
        __syncthreads();
#pragma unroll
        for (int c = 0; c < 4; ++c) {
            int fidx = c * 128 + tid;          // 0..511
            int row = fidx >> 4;
            int col = (fidx & 15) * 4;
            const float* kr = qkv + (size_t)(t0 + kt * 32 + row) * O3 + DIMD + h * HD + col;
            *(float4*)&Ks[row][col] = *(const float4*)kr;
            *(float4*)&Vs[row][col] = *(const float4*)(kr + DIMD);
        }
        __syncthreads();
#pragma unroll 2
        for (int k = 0; k < 32; ++k) {
            float4 k0 = *(const float4*)&Ks[k][qf * 8];
            float4 k1 = *(const float4*)&Ks[k][qf * 8 + 4];
            float s[8];
#pragma unroll
            for (int j = 0; j < 8; ++j) {
                s[j] = q[j][0] * k0.x + q[j][1] * k0.y + q[j][2] * k0.z + q[j][3] * k0.w
                     + q[j][4] * k1.x + q[j][5] * k1.y + q[j][6] * k1.z + q[j][7] * k1.w;
            }
#pragma unroll
            for (int j = 0; j < 8; ++j) {
                s[j] += __shfl_xor(s[j], 1);
                s[j] += __shfl_xor(s[j], 2);
                s[j] += __shfl_xor(s[j], 4);
            }
            float4 v0 = *(const float4*)&Vs[k][qf * 8];
            float4 v1 = *(const float4*)&Vs[k][qf * 8 + 4];
#pragma unroll
            for (int j = 0; j < 8; ++j) {
                float p = __expf(s[j]);
                l[j] += p;
                acc[j][0] += p * v0.x; acc[j][1] += p * v0.y;
                acc[j][2] += p * v0.z; acc[j][3] += p * v0.w;
                acc[j][4] += p * v1.x; acc[j][5] += p * v1.y;
                acc[j][6] += p * v1.z; acc[j][7] += p * v1.w;
            }
        }
    }
#pragma unroll
    for (int j = 0; j < 8; ++j) {
        float inv = 1.f / l[j];
        size_t off = (size_t)(t0 + r0 + j) * DIMD + h * HD + qf * 8;
        ushort8 vh, vl;
#pragma unroll
        for (int i = 0; i < 8; ++i) {
            ushort hh, ll;
            split_bf(acc[j][i] * inv, hh, ll);
            vh[i] = hh; vl[i] = ll;
        }
        *(ushort8*)(Oh + off) = vh;
        *(ushort8*)(Ol + off) = vl;
    }
}

extern "C" void kernel_launch(void* const* d_in, const int* in_sizes, int n_in,
                              void* d_out, int out_size, void* d_ws, size_t ws_size,
                              hipStream_t stream)
{
    const float* x     = (const float*)d_in[0];
    const float* Wg    = (const float*)d_in[1];
    const float* bg    = (const float*)d_in[2];
    const float* Wqkv  = (const float*)d_in[3];
    const float* bqkv  = (const float*)d_in[4];
    const float* Wproj = (const float*)d_in[5];
    const float* bproj = (const float*)d_in[6];
    const float* A     = (const float*)d_in[7];
    const float* ba    = (const float*)d_in[8];
    const float* Bm    = (const float*)d_in[9];
    const float* bb    = (const float*)d_in[10];
    float* out = (float*)d_out;

    char* w = (char*)d_ws;
    float*  topw   = (float*)w;   w += sizeof(float) * TOK * 2;
    int*    topidx = (int*)w;     w += sizeof(int) * TOK * 2;
    float*  hw2    = (float*)w;   w += sizeof(float) * TOK * 32;
    float*  xside  = (float*)w;   w += sizeof(float) * (size_t)TOK * KSIDE;
    float*  wside  = (float*)w;   w += sizeof(float) * (size_t)O3 * KSIDE;
    ushort* Xh     = (ushort*)w;  w += sizeof(ushort) * (size_t)TOK * KQKV;
    ushort* Xl     = (ushort*)w;  w += sizeof(ushort) * (size_t)TOK * KQKV;
    ushort* Whq    = (ushort*)w;  w += sizeof(ushort) * (size_t)O3 * KQKV;
    ushort* Wlq    = (ushort*)w;  w += sizeof(ushort) * (size_t)O3 * KQKV;
    float*  qkv    = (float*)w;   w += sizeof(float) * (size_t)TOK * O3;
    ushort* Wph    = (ushort*)w;  w += sizeof(ushort) * (size_t)DIMD * DIMD;
    ushort* Wpl    = (ushort*)w;  w += sizeof(ushort) * (size_t)DIMD * DIMD;
    // Oh/Ol alias Xh/Xl: X buffers are dead once the qkv GEMM completes, and
    // attention (producer of Oh/Ol) only reads qkv. Keeps ws under ~130 MB.
    ushort* Oh     = Xh;
    ushort* Ol     = Xl;

    router_kernel<<<TOK, 64, 0, stream>>>(x, Wg, bg, topw, topidx);
    lora_h_kernel<<<TOK, 256, 0, stream>>>(x, A, ba, topw, topidx, hw2);
    build_xside<<<TOK, 64, 0, stream>>>(hw2, topw, topidx, xside);
    build_wside<<<O3, 192, 0, stream>>>(Bm, bb, wside);
    convert_x<<<(TOK * (KQKV / 8)) / 256, 256, 0, stream>>>(x, xside, Xh, Xl);
    convert_wqkv<<<(O3 * (KQKV / 8)) / 256, 256, 0, stream>>>(Wqkv, wside, Whq, Wlq);
    convert_wproj<<<(DIMD * DIMD / 8) / 256, 256, 0, stream>>>(Wproj, Wph, Wpl);

    gemm_bf16<<<dim3(O3 / 128, TOK / 128), 256, 0, stream>>>(
        Xh, Xl, Whq, Wlq, bqkv, qkv, O3, KQKV);
    attn_kernel<<<8 * NH * 8, 128, 0, stream>>>(qkv, Oh, Ol);
    gemm_bf16<<<dim3(DIMD / 128, TOK / 128), 256, 0, stream>>>(
        Oh, Ol, Wph, Wpl, bproj, out, DIMD, DIMD);
}

// Round 9
// 392.275 us; speedup vs baseline: 3.9672x; 3.9672x over previous
//
#include <hip/hip_runtime.h>

#define TOK   8192
#define DIMD  768
#define NH    12
#define HD    64
#define NE    8
#define RK    16
#define O3    2304
#define KSIDE 192          // 136 used + zero pad so K_qkv = 768+192 = 960 = 15*64
#define KQKV  960
#define SCALING_F 2.0f
#define SM_SCALE 0.125f
#define PSTR  40           // padded LDS row stride (shorts): 80B rows, 16B-aligned, <=2-way banks

typedef short  short8  __attribute__((ext_vector_type(8)));
typedef ushort ushort8 __attribute__((ext_vector_type(8)));
typedef float  f32x4   __attribute__((ext_vector_type(4)));

__device__ __forceinline__ ushort f2bf_rn(float f) {
    union { float f; uint u; } v; v.f = f;
    uint r = (v.u + 0x7FFFu + ((v.u >> 16) & 1u)) >> 16;
    return (ushort)r;
}
__device__ __forceinline__ void split_bf(float f, ushort& hi, ushort& lo) {
    hi = f2bf_rn(f);
    union { uint u; float f; } h; h.u = (uint)hi << 16;
    lo = f2bf_rn(f - h.f);
}

// ---------------- router: logits -> softmax -> top2 ----------------
__global__ __launch_bounds__(64) void router_kernel(
    const float* __restrict__ x, const float* __restrict__ Wg,
    const float* __restrict__ bg, float* __restrict__ topw, int* __restrict__ topidx)
{
    int t = blockIdx.x;
    int lane = threadIdx.x;
    const float* xr = x + (size_t)t * DIMD;
    float part[NE];
#pragma unroll
    for (int e = 0; e < NE; ++e) part[e] = 0.f;
#pragma unroll
    for (int i = 0; i < DIMD / 64; ++i) {
        int d = i * 64 + lane;
        float xv = xr[d];
#pragma unroll
        for (int e = 0; e < NE; ++e) part[e] += xv * Wg[e * DIMD + d];
    }
#pragma unroll
    for (int e = 0; e < NE; ++e) {
        float v = part[e];
#pragma unroll
        for (int off = 32; off > 0; off >>= 1) v += __shfl_xor(v, off);
        part[e] = v;
    }
    if (lane == 0) {
        float lg[NE], p[NE];
        float mx = -1e30f;
#pragma unroll
        for (int e = 0; e < NE; ++e) { lg[e] = part[e] + bg[e]; mx = fmaxf(mx, lg[e]); }
        float sum = 0.f;
#pragma unroll
        for (int e = 0; e < NE; ++e) { p[e] = __expf(lg[e] - mx); sum += p[e]; }
        float inv = 1.f / sum;
#pragma unroll
        for (int e = 0; e < NE; ++e) p[e] *= inv;
        int i0 = 0;
#pragma unroll
        for (int e = 1; e < NE; ++e) if (p[e] > p[i0]) i0 = e;
        int i1 = (i0 == 0) ? 1 : 0;
#pragma unroll
        for (int e = 0; e < NE; ++e) if (e != i0 && p[e] > p[i1]) i1 = e;
        topw[t * 2 + 0] = p[i0];
        topw[t * 2 + 1] = p[i1];
        topidx[t * 2 + 0] = i0;
        topidx[t * 2 + 1] = i1;
    }
}

// ---------------- LoRA h for the 2 selected experts, combine-weighted ----------------
__global__ __launch_bounds__(256) void lora_h_kernel(
    const float* __restrict__ x, const float* __restrict__ A, const float* __restrict__ ba,
    const float* __restrict__ topw, const int* __restrict__ topidx,
    float* __restrict__ hw2)
{
    __shared__ float xs[DIMD];
    int t = blockIdx.x;
    int tid = threadIdx.x;
    const float* xr = x + (size_t)t * DIMD;
    for (int i = tid; i < DIMD; i += 256) xs[i] = xr[i];
    __syncthreads();
    int outi = tid >> 3;     // 0..31  (k*16 + r)
    int sub  = tid & 7;
    int k = outi >> 4;
    int r = outi & 15;
    int e = topidx[t * 2 + k];
    float w = topw[t * 2 + k];
    const float* Ar = A + ((size_t)e * RK + r) * DIMD;
    float s = 0.f;
    for (int d = sub; d < DIMD; d += 8) s += xs[d] * Ar[d];
    s += __shfl_xor(s, 1);
    s += __shfl_xor(s, 2);
    s += __shfl_xor(s, 4);
    if (sub == 0) hw2[t * 32 + outi] = w * (s + ba[e * RK + r]);
}

// ---------------- dense side-matrix for X: [hw dense(128) | combine(8) | pad] ----------------
__global__ __launch_bounds__(64) void build_xside(
    const float* __restrict__ hw2, const float* __restrict__ topw,
    const int* __restrict__ topidx, float* __restrict__ xside)
{
    int t = blockIdx.x;
    int tid = threadIdx.x;
    float* xr = xside + (size_t)t * KSIDE;
    for (int i = tid; i < KSIDE; i += 64) xr[i] = 0.f;
    __syncthreads();
    if (tid < 32) {
        int k = tid >> 4, r = tid & 15;
        int e = topidx[t * 2 + k];
        xr[e * 16 + r] = hw2[t * 32 + tid];
    } else if (tid < 34) {
        int k = tid - 32;
        xr[128 + topidx[t * 2 + k]] = topw[t * 2 + k];
    }
}

// ---------------- side-matrix for W: [SCALING*Bm(128) | SCALING*bb(8) | pad] ----------------
__global__ __launch_bounds__(192) void build_wside(
    const float* __restrict__ Bm, const float* __restrict__ bb, float* __restrict__ wside)
{
    int o = blockIdx.x;
    int c = threadIdx.x;
    float v;
    if (c < 128) {
        int e = c >> 4, r = c & 15;
        v = SCALING_F * Bm[((size_t)e * O3 + o) * RK + r];
    } else if (c < 136) {
        v = SCALING_F * bb[(c - 128) * O3 + o];
    } else {
        v = 0.f;
    }
    wside[(size_t)o * KSIDE + c] = v;
}

// ---------------- convert combined X=[x|xside] to bf16 hi/lo [TOK][KQKV] ----------------
__global__ __launch_bounds__(256) void convert_x(
    const float* __restrict__ x, const float* __restrict__ xside,
    ushort* __restrict__ Xh, ushort* __restrict__ Xl)
{
    int idx = blockIdx.x * 256 + threadIdx.x;     // one thread per 8 cols
    int row = idx / (KQKV / 8);
    int cp  = idx % (KQKV / 8);
    int c = cp * 8;
    const float* src = (c < DIMD) ? (x + (size_t)row * DIMD + c)
                                  : (xside + (size_t)row * KSIDE + (c - DIMD));
    float4 v0 = *(const float4*)src;
    float4 v1 = *(const float4*)(src + 4);
    float vv[8] = {v0.x, v0.y, v0.z, v0.w, v1.x, v1.y, v1.z, v1.w};
    ushort8 h, l;
#pragma unroll
    for (int i = 0; i < 8; ++i) { ushort hh, ll; split_bf(vv[i], hh, ll); h[i] = hh; l[i] = ll; }
    *(ushort8*)(Xh + (size_t)row * KQKV + c) = h;
    *(ushort8*)(Xl + (size_t)row * KQKV + c) = l;
}

// ---------------- convert combined Wqkv|wside to bf16 hi/lo [O3][KQKV] ----------------
__global__ __launch_bounds__(256) void convert_wqkv(
    const float* __restrict__ Wqkv, const float* __restrict__ wside,
    ushort* __restrict__ Wh, ushort* __restrict__ Wl)
{
    int idx = blockIdx.x * 256 + threadIdx.x;
    int row = idx / (KQKV / 8);
    int cp  = idx % (KQKV / 8);
    int c = cp * 8;
    const float* src = (c < DIMD) ? (Wqkv + (size_t)row * DIMD + c)
                                  : (wside + (size_t)row * KSIDE + (c - DIMD));
    float4 v0 = *(const float4*)src;
    float4 v1 = *(const float4*)(src + 4);
    float vv[8] = {v0.x, v0.y, v0.z, v0.w, v1.x, v1.y, v1.z, v1.w};
    ushort8 h, l;
#pragma unroll
    for (int i = 0; i < 8; ++i) { ushort hh, ll; split_bf(vv[i], hh, ll); h[i] = hh; l[i] = ll; }
    *(ushort8*)(Wh + (size_t)row * KQKV + c) = h;
    *(ushort8*)(Wl + (size_t)row * KQKV + c) = l;
}

// ---------------- convert Wproj to bf16 hi/lo [DIMD][DIMD] ----------------
__global__ __launch_bounds__(256) void convert_wproj(
    const float* __restrict__ Wp, ushort* __restrict__ Wh, ushort* __restrict__ Wl)
{
    int idx = blockIdx.x * 256 + threadIdx.x;
    int c = idx * 8;
    float4 v0 = *(const float4*)(Wp + c);
    float4 v1 = *(const float4*)(Wp + c + 4);
    float vv[8] = {v0.x, v0.y, v0.z, v0.w, v1.x, v1.y, v1.z, v1.w};
    ushort8 h, l;
#pragma unroll
    for (int i = 0; i < 8; ++i) { ushort hh, ll; split_bf(vv[i], hh, ll); h[i] = hh; l[i] = ll; }
    *(ushort8*)(Wh + c) = h;
    *(ushort8*)(Wl + c) = l;
}

// ======== shared GEMM core (3-product compensated bf16 split), two epilogues ========
// A split (Ah+Al), B split (Bh+Bl): AhBh + AlBh + AhBl. 128x128 tile, BK=64,
// 4 waves (2x2), 4x4 frags of mfma_f32_16x16x32_bf16, XOR chunk-swizzled LDS.

#define GEMM_CORE(Ahg, Alg, Bhg, Blg, K)                                          \
    __shared__ __align__(16) ushort Ah[128 * 64];                                 \
    __shared__ __align__(16) ushort Al[128 * 64];                                 \
    __shared__ __align__(16) ushort Bh[128 * 64];                                 \
    __shared__ __align__(16) ushort Bl[128 * 64];                                 \
    const int tid = threadIdx.x;                                                  \
    const int w = tid >> 6, l = tid & 63;                                         \
    const int lr = l & 15, lk = l >> 4;                                           \
    const int wm = w >> 1, wn = w & 1;                                            \
    const int row0 = blockIdx.y * 128, col0 = blockIdx.x * 128;                   \
    f32x4 acc[4][4];                                                              \
    _Pragma("unroll")                                                             \
    for (int m = 0; m < 4; ++m)                                                   \
        _Pragma("unroll")                                                         \
        for (int n = 0; n < 4; ++n) acc[m][n] = (f32x4)(0.f);                     \
    for (int kk = 0; kk < K; kk += 64) {                                          \
        __syncthreads();                                                          \
        _Pragma("unroll")                                                         \
        for (int i = 0; i < 4; ++i) {                                             \
            int q = i * 256 + tid;                                                \
            int row = q >> 3, s = q & 7;                                          \
            int chk = s ^ (row & 7);                                              \
            *(float4*)&Ah[row * 64 + s * 8] =                                     \
                *(const float4*)(Ahg + (size_t)(row0 + row) * K + kk + chk * 8);  \
            *(float4*)&Al[row * 64 + s * 8] =                                     \
                *(const float4*)(Alg + (size_t)(row0 + row) * K + kk + chk * 8);  \
            *(float4*)&Bh[row * 64 + s * 8] =                                     \
                *(const float4*)(Bhg + (size_t)(col0 + row) * K + kk + chk * 8);  \
            *(float4*)&Bl[row * 64 + s * 8] =                                     \
                *(const float4*)(Blg + (size_t)(col0 + row) * K + kk + chk * 8);  \
        }                                                                         \
        __syncthreads();                                                          \
        _Pragma("unroll")                                                         \
        for (int kh = 0; kh < 2; ++kh) {                                          \
            const int slot = (kh * 4 + lk) ^ (lr & 7);                            \
            short8 af[4], alf[4], bfr[4], blf[4];                                 \
            _Pragma("unroll")                                                     \
            for (int m = 0; m < 4; ++m) {                                         \
                int r = wm * 64 + m * 16 + lr;                                    \
                af[m]  = *(const short8*)&Ah[r * 64 + slot * 8];                  \
                alf[m] = *(const short8*)&Al[r * 64 + slot * 8];                  \
            }                                                                     \
            _Pragma("unroll")                                                     \
            for (int n = 0; n < 4; ++n) {                                         \
                int r = wn * 64 + n * 16 + lr;                                    \
                bfr[n] = *(const short8*)&Bh[r * 64 + slot * 8];                  \
                blf[n] = *(const short8*)&Bl[r * 64 + slot * 8];                  \
            }                                                                     \
            _Pragma("unroll")                                                     \
            for (int m = 0; m < 4; ++m)                                           \
                _Pragma("unroll")                                                 \
                for (int n = 0; n < 4; ++n)                                       \
                    acc[m][n] = __builtin_amdgcn_mfma_f32_16x16x32_bf16(af[m], bfr[n], acc[m][n], 0, 0, 0); \
            _Pragma("unroll")                                                     \
            for (int m = 0; m < 4; ++m)                                           \
                _Pragma("unroll")                                                 \
                for (int n = 0; n < 4; ++n)                                       \
                    acc[m][n] = __builtin_amdgcn_mfma_f32_16x16x32_bf16(alf[m], bfr[n], acc[m][n], 0, 0, 0); \
            _Pragma("unroll")                                                     \
            for (int m = 0; m < 4; ++m)                                           \
                _Pragma("unroll")                                                 \
                for (int n = 0; n < 4; ++n)                                       \
                    acc[m][n] = __builtin_amdgcn_mfma_f32_16x16x32_bf16(af[m], blf[n], acc[m][n], 0, 0, 0); \
        }                                                                         \
    }

// qkv GEMM: epilogue scatters bf16 Q (pre-scaled), K row-major and V transposed.
__global__ __launch_bounds__(256) void gemm_qkv(
    const ushort* __restrict__ Ahg, const ushort* __restrict__ Alg,
    const ushort* __restrict__ Bhg, const ushort* __restrict__ Blg,
    const float* __restrict__ bias,
    ushort* __restrict__ Qb, ushort* __restrict__ Kb, ushort* __restrict__ Vtb)
{
    GEMM_CORE(Ahg, Alg, Bhg, Blg, KQKV)
    // C layout: col = lane&15, row = (lane>>4)*4 + reg  [hw-verified]
#pragma unroll
    for (int n = 0; n < 4; ++n) {
        int ccb = col0 + wn * 64 + n * 16;       // 16-aligned -> which/h uniform
        int which = ccb / DIMD;
        int rem = ccb - which * DIMD;
        int h = rem >> 6;
        int d = (rem & 63) + lr;
        float bv = bias[ccb + lr];
#pragma unroll
        for (int m = 0; m < 4; ++m) {
#pragma unroll
            for (int j = 0; j < 4; ++j) {
                int rr = row0 + wm * 64 + m * 16 + lk * 4 + j;
                int b = rr >> 10, s = rr & 1023;
                int bh = b * NH + h;
                float v = acc[m][n][j] + bv;
                if (which == 0)
                    Qb[((size_t)bh * 1024 + s) * 64 + d] = f2bf_rn(v * SM_SCALE);
                else if (which == 1)
                    Kb[((size_t)bh * 1024 + s) * 64 + d] = f2bf_rn(v);
                else
                    Vtb[((size_t)bh * 64 + d) * 1024 + s] = f2bf_rn(v);
            }
        }
    }
}

// proj GEMM: plain fp32 C + bias (unchanged, hw-verified correct).
__global__ __launch_bounds__(256) void gemm_proj(
    const ushort* __restrict__ Ahg, const ushort* __restrict__ Alg,
    const ushort* __restrict__ Bhg, const ushort* __restrict__ Blg,
    const float* __restrict__ bias, float* __restrict__ C, int N)
{
    GEMM_CORE(Ahg, Alg, Bhg, Blg, DIMD)
#pragma unroll
    for (int n = 0; n < 4; ++n) {
        int cc = col0 + wn * 64 + n * 16 + lr;
        float bv = bias[cc];
#pragma unroll
        for (int m = 0; m < 4; ++m) {
#pragma unroll
            for (int j = 0; j < 4; ++j) {
                int rr = row0 + wm * 64 + m * 16 + lk * 4 + j;
                C[(size_t)rr * N + cc] = acc[m][n][j] + bv;
            }
        }
    }
}

// ---------------- MFMA flash attention ----------------
// 4 waves x 16 q-rows (QBLK=64), KBLK=32, fixed-shift softmax (no max tracking;
// |s|<~10 so exp never overflows). Per k-tile per wave: 4 MFMA QK^T + 4 MFMA PV.
// P crosses the QK^T-C-layout -> PV-A-layout mismatch via a per-wave LDS buffer.
// V is staged transposed (from Vtb) so the PV B-frag is a contiguous short8.
__global__ __launch_bounds__(256) void attn_mfma(
    const ushort* __restrict__ Qb, const ushort* __restrict__ Kb,
    const ushort* __restrict__ Vtb,
    ushort* __restrict__ Oh, ushort* __restrict__ Ol)
{
    __shared__ __align__(16) ushort Ksh[32 * 64];       // XOR chunk-swizzled
    __shared__ __align__(16) ushort Vsh[64 * PSTR];     // [d][key], padded
    __shared__ __align__(16) ushort Psh[4][16 * PSTR];  // per-wave [q][key], padded
    const int tid = threadIdx.x;
    const int wv = tid >> 6, l = tid & 63;
    const int lr = l & 15, g = l >> 4;
    const int bh = blockIdx.y;                 // b*NH + h
    const int qt = blockIdx.x;
    const int q0 = qt * 64 + wv * 16;

    // Q A-frags (row = lr, k-chunk = g), Q pre-scaled by SM_SCALE at qkv epilogue
    short8 qA0, qA1;
    {
        const ushort* qp = Qb + ((size_t)bh * 1024 + q0 + lr) * 64 + g * 8;
        qA0 = *(const short8*)(qp);
        qA1 = *(const short8*)(qp + 32);
    }
    f32x4 oacc[4];
#pragma unroll
    for (int i = 0; i < 4; ++i) oacc[i] = (f32x4)(0.f);
    float lp[4] = {0.f, 0.f, 0.f, 0.f};

    const int skey = tid >> 3, scol = tid & 7;
    const int sslot = scol ^ (skey & 7);
    const ushort* kg = Kb + ((size_t)bh * 1024 + skey) * 64 + scol * 8;
    const int vd = tid >> 2, vko = (tid & 3) * 8;
    const ushort* vg = Vtb + ((size_t)bh * 64 + vd) * 1024 + vko;
    ushort* pbase = &Psh[wv][0];
    const int cx = (g ^ (lr & 7)) * 8;          // K-frag chunk, d-half 0
    const int cy = ((4 + g) ^ (lr & 7)) * 8;    // K-frag chunk, d-half 1

    for (int k0 = 0; k0 < 1024; k0 += 32) {
        __syncthreads();
        *(short8*)&Ksh[skey * 64 + sslot * 8] = *(const short8*)(kg + (size_t)k0 * 64);
        *(short8*)&Vsh[vd * PSTR + vko] = *(const short8*)(vg + k0);
        __syncthreads();

        // QK^T: C[q=(g*4+r)][key = kh*16 + lr]
        f32x4 s0 = (f32x4)(0.f), s1 = (f32x4)(0.f);
        {
            short8 kf00 = *(const short8*)&Ksh[lr * 64 + cx];
            short8 kf10 = *(const short8*)&Ksh[(16 + lr) * 64 + cx];
            short8 kf01 = *(const short8*)&Ksh[lr * 64 + cy];
            short8 kf11 = *(const short8*)&Ksh[(16 + lr) * 64 + cy];
            s0 = __builtin_amdgcn_mfma_f32_16x16x32_bf16(qA0, kf00, s0, 0, 0, 0);
            s1 = __builtin_amdgcn_mfma_f32_16x16x32_bf16(qA0, kf10, s1, 0, 0, 0);
            s0 = __builtin_amdgcn_mfma_f32_16x16x32_bf16(qA1, kf01, s0, 0, 0, 0);
            s1 = __builtin_amdgcn_mfma_f32_16x16x32_bf16(qA1, kf11, s1, 0, 0, 0);
        }
        // exp + partial row-sums + P to LDS (bf16)
#pragma unroll
        for (int r = 0; r < 4; ++r) {
            float p0 = __expf(s0[r]);
            float p1 = __expf(s1[r]);
            lp[r] += p0 + p1;
            pbase[(g * 4 + r) * PSTR + lr] = f2bf_rn(p0);
            pbase[(g * 4 + r) * PSTR + 16 + lr] = f2bf_rn(p1);
        }
        // PV: A = P[q=lr][keys g*8..+7], B = Vt[d = dt*16+lr][keys g*8..+7]
        short8 pA = *(const short8*)&pbase[lr * PSTR + g * 8];
#pragma unroll
        for (int dt = 0; dt < 4; ++dt) {
            short8 vB = *(const short8*)&Vsh[(dt * 16 + lr) * PSTR + g * 8];
            oacc[dt] = __builtin_amdgcn_mfma_f32_16x16x32_bf16(pA, vB, oacc[dt], 0, 0, 0);
        }
    }
    // reduce row-sums across the 16 lanes of each group (keys mod 16)
#pragma unroll
    for (int r = 0; r < 4; ++r) {
        float v = lp[r];
        v += __shfl_xor(v, 1);
        v += __shfl_xor(v, 2);
        v += __shfl_xor(v, 4);
        v += __shfl_xor(v, 8);
        lp[r] = 1.f / v;
    }
    const int b = bh / NH, h = bh - b * NH;
    const int tbase = b * 1024 + q0;
#pragma unroll
    for (int dt = 0; dt < 4; ++dt) {
        int d = dt * 16 + lr;
#pragma unroll
        for (int r = 0; r < 4; ++r) {
            float v = oacc[dt][r] * lp[r];
            ushort hh, ll;
            split_bf(v, hh, ll);
            size_t off = (size_t)(tbase + g * 4 + r) * DIMD + h * HD + d;
            Oh[off] = hh;
            Ol[off] = ll;
        }
    }
}

extern "C" void kernel_launch(void* const* d_in, const int* in_sizes, int n_in,
                              void* d_out, int out_size, void* d_ws, size_t ws_size,
                              hipStream_t stream)
{
    const float* x     = (const float*)d_in[0];
    const float* Wg    = (const float*)d_in[1];
    const float* bg    = (const float*)d_in[2];
    const float* Wqkv  = (const float*)d_in[3];
    const float* bqkv  = (const float*)d_in[4];
    const float* Wproj = (const float*)d_in[5];
    const float* bproj = (const float*)d_in[6];
    const float* A     = (const float*)d_in[7];
    const float* ba    = (const float*)d_in[8];
    const float* Bm    = (const float*)d_in[9];
    const float* bb    = (const float*)d_in[10];
    float* out = (float*)d_out;

    char* w = (char*)d_ws;
    float*  topw   = (float*)w;   w += sizeof(float) * TOK * 2;
    int*    topidx = (int*)w;     w += sizeof(int) * TOK * 2;
    float*  hw2    = (float*)w;   w += sizeof(float) * TOK * 32;
    float*  xside  = (float*)w;   w += sizeof(float) * (size_t)TOK * KSIDE;
    float*  wside  = (float*)w;   w += sizeof(float) * (size_t)O3 * KSIDE;
    ushort* Xh     = (ushort*)w;  w += sizeof(ushort) * (size_t)TOK * KQKV;
    ushort* Xl     = (ushort*)w;  w += sizeof(ushort) * (size_t)TOK * KQKV;
    ushort* Whq    = (ushort*)w;  w += sizeof(ushort) * (size_t)O3 * KQKV;
    ushort* Wlq    = (ushort*)w;  w += sizeof(ushort) * (size_t)O3 * KQKV;
    ushort* Qb     = (ushort*)w;  w += sizeof(ushort) * (size_t)TOK * DIMD;
    ushort* Kb     = (ushort*)w;  w += sizeof(ushort) * (size_t)TOK * DIMD;
    ushort* Vtb    = (ushort*)w;  w += sizeof(ushort) * (size_t)TOK * DIMD;
    ushort* Wph    = (ushort*)w;  w += sizeof(ushort) * (size_t)DIMD * DIMD;
    ushort* Wpl    = (ushort*)w;  w += sizeof(ushort) * (size_t)DIMD * DIMD;
    // Oh/Ol alias Xh/Xl (dead after the qkv GEMM).
    ushort* Oh     = Xh;
    ushort* Ol     = Xl;

    router_kernel<<<TOK, 64, 0, stream>>>(x, Wg, bg, topw, topidx);
    lora_h_kernel<<<TOK, 256, 0, stream>>>(x, A, ba, topw, topidx, hw2);
    build_xside<<<TOK, 64, 0, stream>>>(hw2, topw, topidx, xside);
    build_wside<<<O3, 192, 0, stream>>>(Bm, bb, wside);
    convert_x<<<(TOK * (KQKV / 8)) / 256, 256, 0, stream>>>(x, xside, Xh, Xl);
    convert_wqkv<<<(O3 * (KQKV / 8)) / 256, 256, 0, stream>>>(Wqkv, wside, Whq, Wlq);
    convert_wproj<<<(DIMD * DIMD / 8) / 256, 256, 0, stream>>>(Wproj, Wph, Wpl);

    gemm_qkv<<<dim3(O3 / 128, TOK / 128), 256, 0, stream>>>(
        Xh, Xl, Whq, Wlq, bqkv, Qb, Kb, Vtb);
    attn_mfma<<<dim3(16, NH * 8), 256, 0, stream>>>(Qb, Kb, Vtb, Oh, Ol);
    gemm_proj<<<dim3(DIMD / 128, TOK / 128), 256, 0, stream>>>(
        Oh, Ol, Wph, Wpl, bproj, out, DIMD);
}

// Round 11
// 373.154 us; speedup vs baseline: 4.1705x; 1.0512x over previous
//
#include <hip/hip_runtime.h>

#define TOK   8192
#define DIMD  768
#define NH    12
#define HD    64
#define NE    8
#define RK    16
#define O3    2304
#define KSIDE 192          // 136 used + zero pad so K_qkv = 768+192 = 960 = 15*64
#define KQKV  960
#define SCALING_F 2.0f
#define SM_SCALE 0.125f
#define PSTR  40           // padded LDS row stride (shorts): 80B rows, 16B-aligned, <=2-way banks

typedef short  short8  __attribute__((ext_vector_type(8)));
typedef ushort ushort8 __attribute__((ext_vector_type(8)));
typedef float  f32x4   __attribute__((ext_vector_type(4)));

__device__ __forceinline__ ushort f2bf_rn(float f) {
    union { float f; uint u; } v; v.f = f;
    uint r = (v.u + 0x7FFFu + ((v.u >> 16) & 1u)) >> 16;
    return (ushort)r;
}
__device__ __forceinline__ void split_bf(float f, ushort& hi, ushort& lo) {
    hi = f2bf_rn(f);
    union { uint u; float f; } h; h.u = (uint)hi << 16;
    lo = f2bf_rn(f - h.f);
}

// ---------------- router: logits -> softmax -> top2 ----------------
__global__ __launch_bounds__(64) void router_kernel(
    const float* __restrict__ x, const float* __restrict__ Wg,
    const float* __restrict__ bg, float* __restrict__ topw, int* __restrict__ topidx)
{
    int t = blockIdx.x;
    int lane = threadIdx.x;
    const float* xr = x + (size_t)t * DIMD;
    float part[NE];
#pragma unroll
    for (int e = 0; e < NE; ++e) part[e] = 0.f;
#pragma unroll
    for (int i = 0; i < DIMD / 64; ++i) {
        int d = i * 64 + lane;
        float xv = xr[d];
#pragma unroll
        for (int e = 0; e < NE; ++e) part[e] += xv * Wg[e * DIMD + d];
    }
#pragma unroll
    for (int e = 0; e < NE; ++e) {
        float v = part[e];
#pragma unroll
        for (int off = 32; off > 0; off >>= 1) v += __shfl_xor(v, off);
        part[e] = v;
    }
    if (lane == 0) {
        float lg[NE], p[NE];
        float mx = -1e30f;
#pragma unroll
        for (int e = 0; e < NE; ++e) { lg[e] = part[e] + bg[e]; mx = fmaxf(mx, lg[e]); }
        float sum = 0.f;
#pragma unroll
        for (int e = 0; e < NE; ++e) { p[e] = __expf(lg[e] - mx); sum += p[e]; }
        float inv = 1.f / sum;
#pragma unroll
        for (int e = 0; e < NE; ++e) p[e] *= inv;
        int i0 = 0;
#pragma unroll
        for (int e = 1; e < NE; ++e) if (p[e] > p[i0]) i0 = e;
        int i1 = (i0 == 0) ? 1 : 0;
#pragma unroll
        for (int e = 0; e < NE; ++e) if (e != i0 && p[e] > p[i1]) i1 = e;
        topw[t * 2 + 0] = p[i0];
        topw[t * 2 + 1] = p[i1];
        topidx[t * 2 + 0] = i0;
        topidx[t * 2 + 1] = i1;
    }
}

// ---------------- LoRA h for the 2 selected experts, combine-weighted ----------------
__global__ __launch_bounds__(256) void lora_h_kernel(
    const float* __restrict__ x, const float* __restrict__ A, const float* __restrict__ ba,
    const float* __restrict__ topw, const int* __restrict__ topidx,
    float* __restrict__ hw2)
{
    __shared__ float xs[DIMD];
    int t = blockIdx.x;
    int tid = threadIdx.x;
    const float* xr = x + (size_t)t * DIMD;
    for (int i = tid; i < DIMD; i += 256) xs[i] = xr[i];
    __syncthreads();
    int outi = tid >> 3;     // 0..31  (k*16 + r)
    int sub  = tid & 7;
    int k = outi >> 4;
    int r = outi & 15;
    int e = topidx[t * 2 + k];
    float w = topw[t * 2 + k];
    const float* Ar = A + ((size_t)e * RK + r) * DIMD;
    float s = 0.f;
    for (int d = sub; d < DIMD; d += 8) s += xs[d] * Ar[d];
    s += __shfl_xor(s, 1);
    s += __shfl_xor(s, 2);
    s += __shfl_xor(s, 4);
    if (sub == 0) hw2[t * 32 + outi] = w * (s + ba[e * RK + r]);
}

// ---------------- dense side-matrix for X: [hw dense(128) | combine(8) | pad] ----------------
__global__ __launch_bounds__(64) void build_xside(
    const float* __restrict__ hw2, const float* __restrict__ topw,
    const int* __restrict__ topidx, float* __restrict__ xside)
{
    int t = blockIdx.x;
    int tid = threadIdx.x;
    float* xr = xside + (size_t)t * KSIDE;
    for (int i = tid; i < KSIDE; i += 64) xr[i] = 0.f;
    __syncthreads();
    if (tid < 32) {
        int k = tid >> 4, r = tid & 15;
        int e = topidx[t * 2 + k];
        xr[e * 16 + r] = hw2[t * 32 + tid];
    } else if (tid < 34) {
        int k = tid - 32;
        xr[128 + topidx[t * 2 + k]] = topw[t * 2 + k];
    }
}

// ---------------- side-matrix for W: [SCALING*Bm(128) | SCALING*bb(8) | pad] ----------------
__global__ __launch_bounds__(192) void build_wside(
    const float* __restrict__ Bm, const float* __restrict__ bb, float* __restrict__ wside)
{
    int o = blockIdx.x;
    int c = threadIdx.x;
    float v;
    if (c < 128) {
        int e = c >> 4, r = c & 15;
        v = SCALING_F * Bm[((size_t)e * O3 + o) * RK + r];
    } else if (c < 136) {
        v = SCALING_F * bb[(c - 128) * O3 + o];
    } else {
        v = 0.f;
    }
    wside[(size_t)o * KSIDE + c] = v;
}

// ---------------- convert combined X=[x|xside] to bf16 hi/lo [TOK][KQKV] ----------------
__global__ __launch_bounds__(256) void convert_x(
    const float* __restrict__ x, const float* __restrict__ xside,
    ushort* __restrict__ Xh, ushort* __restrict__ Xl)
{
    int idx = blockIdx.x * 256 + threadIdx.x;     // one thread per 8 cols
    int row = idx / (KQKV / 8);
    int cp  = idx % (KQKV / 8);
    int c = cp * 8;
    const float* src = (c < DIMD) ? (x + (size_t)row * DIMD + c)
                                  : (xside + (size_t)row * KSIDE + (c - DIMD));
    float4 v0 = *(const float4*)src;
    float4 v1 = *(const float4*)(src + 4);
    float vv[8] = {v0.x, v0.y, v0.z, v0.w, v1.x, v1.y, v1.z, v1.w};
    ushort8 h, l;
#pragma unroll
    for (int i = 0; i < 8; ++i) { ushort hh, ll; split_bf(vv[i], hh, ll); h[i] = hh; l[i] = ll; }
    *(ushort8*)(Xh + (size_t)row * KQKV + c) = h;
    *(ushort8*)(Xl + (size_t)row * KQKV + c) = l;
}

// ---------------- convert combined Wqkv|wside to single bf16 [O3][KQKV] ----------------
// (W-lo dropped for the qkv GEMM: its error contribution is below the bf16
// rounding already applied to Q/K/V at the epilogue — absmax floor unchanged.)
__global__ __launch_bounds__(256) void convert_wqkv(
    const float* __restrict__ Wqkv, const float* __restrict__ wside,
    ushort* __restrict__ Wh)
{
    int idx = blockIdx.x * 256 + threadIdx.x;
    int row = idx / (KQKV / 8);
    int cp  = idx % (KQKV / 8);
    int c = cp * 8;
    const float* src = (c < DIMD) ? (Wqkv + (size_t)row * DIMD + c)
                                  : (wside + (size_t)row * KSIDE + (c - DIMD));
    float4 v0 = *(const float4*)src;
    float4 v1 = *(const float4*)(src + 4);
    float vv[8] = {v0.x, v0.y, v0.z, v0.w, v1.x, v1.y, v1.z, v1.w};
    ushort8 h;
#pragma unroll
    for (int i = 0; i < 8; ++i) h[i] = f2bf_rn(vv[i]);
    *(ushort8*)(Wh + (size_t)row * KQKV + c) = h;
}

// ---------------- convert Wproj to bf16 hi/lo [DIMD][DIMD] ----------------
__global__ __launch_bounds__(256) void convert_wproj(
    const float* __restrict__ Wp, ushort* __restrict__ Wh, ushort* __restrict__ Wl)
{
    int idx = blockIdx.x * 256 + threadIdx.x;
    int c = idx * 8;
    float4 v0 = *(const float4*)(Wp + c);
    float4 v1 = *(const float4*)(Wp + c + 4);
    float vv[8] = {v0.x, v0.y, v0.z, v0.w, v1.x, v1.y, v1.z, v1.w};
    ushort8 h, l;
#pragma unroll
    for (int i = 0; i < 8; ++i) { ushort hh, ll; split_bf(vv[i], hh, ll); h[i] = hh; l[i] = ll; }
    *(ushort8*)(Wh + c) = h;
    *(ushort8*)(Wl + c) = l;
}

// ======== GEMM cores: 128x128 tile, BK=64, 4 waves (2x2), mfma_f32_16x16x32_bf16 ========
// XOR chunk-swizzled LDS. Bijective XCD swizzle (nwg % 8 == 0 for both grids):
// each XCD gets a contiguous chunk of tiles -> W panel + X row-panels L2-resident.

#define GEMM_PROLOG                                                               \
    const int tid = threadIdx.x;                                                  \
    const int w = tid >> 6, l = tid & 63;                                         \
    const int lr = l & 15, lk = l >> 4;                                           \
    const int wm = w >> 1, wn = w & 1;                                            \
    int bx, by;                                                                   \
    {                                                                             \
        int nx = gridDim.x;                                                       \
        int nwg = nx * gridDim.y;                                                 \
        int lin = blockIdx.y * nx + blockIdx.x;                                   \
        int swz = (lin & 7) * (nwg >> 3) + (lin >> 3);                            \
        bx = swz % nx; by = swz / nx;                                             \
    }                                                                             \
    const int row0 = by * 128, col0 = bx * 128;

// 2-product core (x split, W single-bf16): AhBh + AlBh. LDS 48 KiB -> 3 blocks/CU.
#define GEMM_CORE2(Ahg, Alg, Bhg, K)                                              \
    __shared__ __align__(16) ushort Ah[128 * 64];                                 \
    __shared__ __align__(16) ushort Al[128 * 64];                                 \
    __shared__ __align__(16) ushort Bh[128 * 64];                                 \
    GEMM_PROLOG                                                                   \
    f32x4 acc[4][4];                                                              \
    _Pragma("unroll")                                                             \
    for (int m = 0; m < 4; ++m)                                                   \
        _Pragma("unroll")                                                         \
        for (int n = 0; n < 4; ++n) acc[m][n] = (f32x4)(0.f);                     \
    for (int kk = 0; kk < K; kk += 64) {                                          \
        __syncthreads();                                                          \
        _Pragma("unroll")                                                         \
        for (int i = 0; i < 4; ++i) {                                             \
            int q = i * 256 + tid;                                                \
            int row = q >> 3, s = q & 7;                                          \
            int chk = s ^ (row & 7);                                              \
            *(float4*)&Ah[row * 64 + s * 8] =                                     \
                *(const float4*)(Ahg + (size_t)(row0 + row) * K + kk + chk * 8);  \
            *(float4*)&Al[row * 64 + s * 8] =                                     \
                *(const float4*)(Alg + (size_t)(row0 + row) * K + kk + chk * 8);  \
            *(float4*)&Bh[row * 64 + s * 8] =                                     \
                *(const float4*)(Bhg + (size_t)(col0 + row) * K + kk + chk * 8);  \
        }                                                                         \
        __syncthreads();                                                          \
        _Pragma("unroll")                                                         \
        for (int kh = 0; kh < 2; ++kh) {                                          \
            const int slot = (kh * 4 + lk) ^ (lr & 7);                            \
            short8 af[4], alf[4], bfr[4];                                         \
            _Pragma("unroll")                                                     \
            for (int m = 0; m < 4; ++m) {                                         \
                int r = wm * 64 + m * 16 + lr;                                    \
                af[m]  = *(const short8*)&Ah[r * 64 + slot * 8];                  \
                alf[m] = *(const short8*)&Al[r * 64 + slot * 8];                  \
            }                                                                     \
            _Pragma("unroll")                                                     \
            for (int n = 0; n < 4; ++n) {                                         \
                int r = wn * 64 + n * 16 + lr;                                    \
                bfr[n] = *(const short8*)&Bh[r * 64 + slot * 8];                  \
            }                                                                     \
            _Pragma("unroll")                                                     \
            for (int m = 0; m < 4; ++m)                                           \
                _Pragma("unroll")                                                 \
                for (int n = 0; n < 4; ++n)                                       \
                    acc[m][n] = __builtin_amdgcn_mfma_f32_16x16x32_bf16(af[m], bfr[n], acc[m][n], 0, 0, 0); \
            _Pragma("unroll")                                                     \
            for (int m = 0; m < 4; ++m)                                           \
                _Pragma("unroll")                                                 \
                for (int n = 0; n < 4; ++n)                                       \
                    acc[m][n] = __builtin_amdgcn_mfma_f32_16x16x32_bf16(alf[m], bfr[n], acc[m][n], 0, 0, 0); \
        }                                                                         \
    }

// 3-product core (both split): AhBh + AlBh + AhBl (proj: W error hits output directly).
#define GEMM_CORE3(Ahg, Alg, Bhg, Blg, K)                                         \
    __shared__ __align__(16) ushort Ah[128 * 64];                                 \
    __shared__ __align__(16) ushort Al[128 * 64];                                 \
    __shared__ __align__(16) ushort Bh[128 * 64];                                 \
    __shared__ __align__(16) ushort Bl[128 * 64];                                 \
    GEMM_PROLOG                                                                   \
    f32x4 acc[4][4];                                                              \
    _Pragma("unroll")                                                             \
    for (int m = 0; m < 4; ++m)                                                   \
        _Pragma("unroll")                                                         \
        for (int n = 0; n < 4; ++n) acc[m][n] = (f32x4)(0.f);                     \
    for (int kk = 0; kk < K; kk += 64) {                                          \
        __syncthreads();                                                          \
        _Pragma("unroll")                                                         \
        for (int i = 0; i < 4; ++i) {                                             \
            int q = i * 256 + tid;                                                \
            int row = q >> 3, s = q & 7;                                          \
            int chk = s ^ (row & 7);                                              \
            *(float4*)&Ah[row * 64 + s * 8] =                                     \
                *(const float4*)(Ahg + (size_t)(row0 + row) * K + kk + chk * 8);  \
            *(float4*)&Al[row * 64 + s * 8] =                                     \
                *(const float4*)(Alg + (size_t)(row0 + row) * K + kk + chk * 8);  \
            *(float4*)&Bh[row * 64 + s * 8] =                                     \
                *(const float4*)(Bhg + (size_t)(col0 + row) * K + kk + chk * 8);  \
            *(float4*)&Bl[row * 64 + s * 8] =                                     \
                *(const float4*)(Blg + (size_t)(col0 + row) * K + kk + chk * 8);  \
        }                                                                         \
        __syncthreads();                                                          \
        _Pragma("unroll")                                                         \
        for (int kh = 0; kh < 2; ++kh) {                                          \
            const int slot = (kh * 4 + lk) ^ (lr & 7);                            \
            short8 af[4], alf[4], bfr[4], blf[4];                                 \
            _Pragma("unroll")                                                     \
            for (int m = 0; m < 4; ++m) {                                         \
                int r = wm * 64 + m * 16 + lr;                                    \
                af[m]  = *(const short8*)&Ah[r * 64 + slot * 8];                  \
                alf[m] = *(const short8*)&Al[r * 64 + slot * 8];                  \
            }                                                                     \
            _Pragma("unroll")                                                     \
            for (int n = 0; n < 4; ++n) {                                         \
                int r = wn * 64 + n * 16 + lr;                                    \
                bfr[n] = *(const short8*)&Bh[r * 64 + slot * 8];                  \
                blf[n] = *(const short8*)&Bl[r * 64 + slot * 8];                  \
            }                                                                     \
            _Pragma("unroll")                                                     \
            for (int m = 0; m < 4; ++m)                                           \
                _Pragma("unroll")                                                 \
                for (int n = 0; n < 4; ++n)                                       \
                    acc[m][n] = __builtin_amdgcn_mfma_f32_16x16x32_bf16(af[m], bfr[n], acc[m][n], 0, 0, 0); \
            _Pragma("unroll")                                                     \
            for (int m = 0; m < 4; ++m)                                           \
                _Pragma("unroll")                                                 \
                for (int n = 0; n < 4; ++n)                                       \
                    acc[m][n] = __builtin_amdgcn_mfma_f32_16x16x32_bf16(alf[m], bfr[n], acc[m][n], 0, 0, 0); \
            _Pragma("unroll")                                                     \
            for (int m = 0; m < 4; ++m)                                           \
                _Pragma("unroll")                                                 \
                for (int n = 0; n < 4; ++n)                                       \
                    acc[m][n] = __builtin_amdgcn_mfma_f32_16x16x32_bf16(af[m], blf[n], acc[m][n], 0, 0, 0); \
        }                                                                         \
    }

// qkv GEMM: epilogue scatters bf16 Q (pre-scaled), K row-major and V transposed.
__global__ __launch_bounds__(256) void gemm_qkv(
    const ushort* __restrict__ Ahg, const ushort* __restrict__ Alg,
    const ushort* __restrict__ Bhg,
    const float* __restrict__ bias,
    ushort* __restrict__ Qb, ushort* __restrict__ Kb, ushort* __restrict__ Vtb)
{
    GEMM_CORE2(Ahg, Alg, Bhg, KQKV)
    // C layout: col = lane&15, row = (lane>>4)*4 + reg  [hw-verified]
#pragma unroll
    for (int n = 0; n < 4; ++n) {
        int ccb = col0 + wn * 64 + n * 16;       // 16-aligned -> which/h uniform
        int which = ccb / DIMD;
        int rem = ccb - which * DIMD;
        int h = rem >> 6;
        int d = (rem & 63) + lr;
        float bv = bias[ccb + lr];
#pragma unroll
        for (int m = 0; m < 4; ++m) {
#pragma unroll
            for (int j = 0; j < 4; ++j) {
                int rr = row0 + wm * 64 + m * 16 + lk * 4 + j;
                int b = rr >> 10, s = rr & 1023;
                int bh = b * NH + h;
                float v = acc[m][n][j] + bv;
                if (which == 0)
                    Qb[((size_t)bh * 1024 + s) * 64 + d] = f2bf_rn(v * SM_SCALE);
                else if (which == 1)
                    Kb[((size_t)bh * 1024 + s) * 64 + d] = f2bf_rn(v);
                else
                    Vtb[((size_t)bh * 64 + d) * 1024 + s] = f2bf_rn(v);
            }
        }
    }
}

// proj GEMM: plain fp32 C + bias.
__global__ __launch_bounds__(256) void gemm_proj(
    const ushort* __restrict__ Ahg, const ushort* __restrict__ Alg,
    const ushort* __restrict__ Bhg, const ushort* __restrict__ Blg,
    const float* __restrict__ bias, float* __restrict__ C, int N)
{
    GEMM_CORE3(Ahg, Alg, Bhg, Blg, DIMD)
#pragma unroll
    for (int n = 0; n < 4; ++n) {
        int cc = col0 + wn * 64 + n * 16 + lr;
        float bv = bias[cc];
#pragma unroll
        for (int m = 0; m < 4; ++m) {
#pragma unroll
            for (int j = 0; j < 4; ++j) {
                int rr = row0 + wm * 64 + m * 16 + lk * 4 + j;
                C[(size_t)rr * N + cc] = acc[m][n][j] + bv;
            }
        }
    }
}

// ---------------- MFMA flash attention (hw-validated round 9) ----------------
__global__ __launch_bounds__(256) void attn_mfma(
    const ushort* __restrict__ Qb, const ushort* __restrict__ Kb,
    const ushort* __restrict__ Vtb,
    ushort* __restrict__ Oh, ushort* __restrict__ Ol)
{
    __shared__ __align__(16) ushort Ksh[32 * 64];       // XOR chunk-swizzled
    __shared__ __align__(16) ushort Vsh[64 * PSTR];     // [d][key], padded
    __shared__ __align__(16) ushort Psh[4][16 * PSTR];  // per-wave [q][key], padded
    const int tid = threadIdx.x;
    const int wv = tid >> 6, l = tid & 63;
    const int lr = l & 15, g = l >> 4;
    const int bh = blockIdx.y;                 // b*NH + h
    const int qt = blockIdx.x;
    const int q0 = qt * 64 + wv * 16;

    short8 qA0, qA1;
    {
        const ushort* qp = Qb + ((size_t)bh * 1024 + q0 + lr) * 64 + g * 8;
        qA0 = *(const short8*)(qp);
        qA1 = *(const short8*)(qp + 32);
    }
    f32x4 oacc[4];
#pragma unroll
    for (int i = 0; i < 4; ++i) oacc[i] = (f32x4)(0.f);
    float lp[4] = {0.f, 0.f, 0.f, 0.f};

    const int skey = tid >> 3, scol = tid & 7;
    const int sslot = scol ^ (skey & 7);
    const ushort* kg = Kb + ((size_t)bh * 1024 + skey) * 64 + scol * 8;
    const int vd = tid >> 2, vko = (tid & 3) * 8;
    const ushort* vg = Vtb + ((size_t)bh * 64 + vd) * 1024 + vko;
    ushort* pbase = &Psh[wv][0];
    const int cx = (g ^ (lr & 7)) * 8;          // K-frag chunk, d-half 0
    const int cy = ((4 + g) ^ (lr & 7)) * 8;    // K-frag chunk, d-half 1

    for (int k0 = 0; k0 < 1024; k0 += 32) {
        __syncthreads();
        *(short8*)&Ksh[skey * 64 + sslot * 8] = *(const short8*)(kg + (size_t)k0 * 64);
        *(short8*)&Vsh[vd * PSTR + vko] = *(const short8*)(vg + k0);
        __syncthreads();

        // QK^T: C[q=(g*4+r)][key = kh*16 + lr]
        f32x4 s0 = (f32x4)(0.f), s1 = (f32x4)(0.f);
        {
            short8 kf00 = *(const short8*)&Ksh[lr * 64 + cx];
            short8 kf10 = *(const short8*)&Ksh[(16 + lr) * 64 + cx];
            short8 kf01 = *(const short8*)&Ksh[lr * 64 + cy];
            short8 kf11 = *(const short8*)&Ksh[(16 + lr) * 64 + cy];
            s0 = __builtin_amdgcn_mfma_f32_16x16x32_bf16(qA0, kf00, s0, 0, 0, 0);
            s1 = __builtin_amdgcn_mfma_f32_16x16x32_bf16(qA0, kf10, s1, 0, 0, 0);
            s0 = __builtin_amdgcn_mfma_f32_16x16x32_bf16(qA1, kf01, s0, 0, 0, 0);
            s1 = __builtin_amdgcn_mfma_f32_16x16x32_bf16(qA1, kf11, s1, 0, 0, 0);
        }
#pragma unroll
        for (int r = 0; r < 4; ++r) {
            float p0 = __expf(s0[r]);
            float p1 = __expf(s1[r]);
            lp[r] += p0 + p1;
            pbase[(g * 4 + r) * PSTR + lr] = f2bf_rn(p0);
            pbase[(g * 4 + r) * PSTR + 16 + lr] = f2bf_rn(p1);
        }
        short8 pA = *(const short8*)&pbase[lr * PSTR + g * 8];
#pragma unroll
        for (int dt = 0; dt < 4; ++dt) {
            short8 vB = *(const short8*)&Vsh[(dt * 16 + lr) * PSTR + g * 8];
            oacc[dt] = __builtin_amdgcn_mfma_f32_16x16x32_bf16(pA, vB, oacc[dt], 0, 0, 0);
        }
    }
#pragma unroll
    for (int r = 0; r < 4; ++r) {
        float v = lp[r];
        v += __shfl_xor(v, 1);
        v += __shfl_xor(v, 2);
        v += __shfl_xor(v, 4);
        v += __shfl_xor(v, 8);
        lp[r] = 1.f / v;
    }
    const int b = bh / NH, h = bh - b * NH;
    const int tbase = b * 1024 + q0;
#pragma unroll
    for (int dt = 0; dt < 4; ++dt) {
        int d = dt * 16 + lr;
#pragma unroll
        for (int r = 0; r < 4; ++r) {
            float v = oacc[dt][r] * lp[r];
            ushort hh, ll;
            split_bf(v, hh, ll);
            size_t off = (size_t)(tbase + g * 4 + r) * DIMD + h * HD + d;
            Oh[off] = hh;
            Ol[off] = ll;
        }
    }
}

extern "C" void kernel_launch(void* const* d_in, const int* in_sizes, int n_in,
                              void* d_out, int out_size, void* d_ws, size_t ws_size,
                              hipStream_t stream)
{
    const float* x     = (const float*)d_in[0];
    const float* Wg    = (const float*)d_in[1];
    const float* bg    = (const float*)d_in[2];
    const float* Wqkv  = (const float*)d_in[3];
    const float* bqkv  = (const float*)d_in[4];
    const float* Wproj = (const float*)d_in[5];
    const float* bproj = (const float*)d_in[6];
    const float* A     = (const float*)d_in[7];
    const float* ba    = (const float*)d_in[8];
    const float* Bm    = (const float*)d_in[9];
    const float* bb    = (const float*)d_in[10];
    float* out = (float*)d_out;

    char* w = (char*)d_ws;
    float*  topw   = (float*)w;   w += sizeof(float) * TOK * 2;
    int*    topidx = (int*)w;     w += sizeof(int) * TOK * 2;
    float*  hw2    = (float*)w;   w += sizeof(float) * TOK * 32;
    float*  xside  = (float*)w;   w += sizeof(float) * (size_t)TOK * KSIDE;
    float*  wside  = (float*)w;   w += sizeof(float) * (size_t)O3 * KSIDE;
    ushort* Xh     = (ushort*)w;  w += sizeof(ushort) * (size_t)TOK * KQKV;
    ushort* Xl     = (ushort*)w;  w += sizeof(ushort) * (size_t)TOK * KQKV;
    ushort* Whq    = (ushort*)w;  w += sizeof(ushort) * (size_t)O3 * KQKV;
    ushort* Qb     = (ushort*)w;  w += sizeof(ushort) * (size_t)TOK * DIMD;
    ushort* Kb     = (ushort*)w;  w += sizeof(ushort) * (size_t)TOK * DIMD;
    ushort* Vtb    = (ushort*)w;  w += sizeof(ushort) * (size_t)TOK * DIMD;
    ushort* Wph    = (ushort*)w;  w += sizeof(ushort) * (size_t)DIMD * DIMD;
    ushort* Wpl    = (ushort*)w;  w += sizeof(ushort) * (size_t)DIMD * DIMD;
    // Oh/Ol alias Xh/Xl (dead after the qkv GEMM).
    ushort* Oh     = Xh;
    ushort* Ol     = Xl;

    router_kernel<<<TOK, 64, 0, stream>>>(x, Wg, bg, topw, topidx);
    lora_h_kernel<<<TOK, 256, 0, stream>>>(x, A, ba, topw, topidx, hw2);
    build_xside<<<TOK, 64, 0, stream>>>(hw2, topw, topidx, xside);
    build_wside<<<O3, 192, 0, stream>>>(Bm, bb, wside);
    convert_x<<<(TOK * (KQKV / 8)) / 256, 256, 0, stream>>>(x, xside, Xh, Xl);
    convert_wqkv<<<(O3 * (KQKV / 8)) / 256, 256, 0, stream>>>(Wqkv, wside, Whq);
    convert_wproj<<<(DIMD * DIMD / 8) / 256, 256, 0, stream>>>(Wproj, Wph, Wpl);

    gemm_qkv<<<dim3(O3 / 128, TOK / 128), 256, 0, stream>>>(
        Xh, Xl, Whq, bqkv, Qb, Kb, Vtb);
    attn_mfma<<<dim3(16, NH * 8), 256, 0, stream>>>(Qb, Kb, Vtb, Oh, Ol);
    gemm_proj<<<dim3(DIMD / 128, TOK / 128), 256, 0, stream>>>(
        Oh, Ol, Wph, Wpl, bproj, out, DIMD);
}